// Round 6
// baseline (384.455 us; speedup 1.0000x reference)
//
#include <hip/hip_runtime.h>
#include <hip/hip_bf16.h>

#define DEV static __device__ __forceinline__

constexpr int B = 4, S = 2048, H = 8, D = 128, FH = 512;
constexpr int M = B * S;   // 8192
constexpr int SC = 64;     // scan/prefix chunk length
constexpr int NCH = S / SC; // 32

typedef __attribute__((ext_vector_type(8))) short short8;
typedef __attribute__((ext_vector_type(4))) float f32x4;

DEV float sigmoidf_(float x) { return 1.0f / (1.0f + __expf(-x)); }
DEV float b2f(unsigned short u) { union { unsigned int i; float f; } x; x.i = (unsigned int)u << 16; return x.f; }
DEV unsigned short f2bu(float f) { __hip_bfloat16 b = __float2bfloat16(f); union { __hip_bfloat16 b; unsigned short u; } x; x.b = b; return x.u; }

// ---------------- zero stats buffers (re-poisoned to 0xAA every launch) --------
__global__ void k_zero(float4* __restrict__ p) {
  p[blockIdx.x * 256 + threadIdx.x] = float4{0.f, 0.f, 0.f, 0.f};
}

// ---------------- weight convert + transpose: W[h][k][n] f32 -> Wt[h][n][k] bf16
__global__ void k_wcvt(const float* __restrict__ W, __hip_bfloat16* __restrict__ Wt,
                       int K, int N) {
  __shared__ float t[32][33];
  int h = blockIdx.z;
  int k0 = blockIdx.x * 32, n0 = blockIdx.y * 32;
  int tx = threadIdx.x, ty = threadIdx.y;  // 32 x 8
  #pragma unroll
  for (int r = 0; r < 32; r += 8)
    t[ty + r][tx] = W[((size_t)h * K + k0 + ty + r) * N + n0 + tx];
  __syncthreads();
  #pragma unroll
  for (int r = 0; r < 32; r += 8)
    Wt[((size_t)h * N + n0 + ty + r) * K + k0 + tx] = __float2bfloat16(t[tx][ty + r]);
}

// ---------------- prefix phase 1: per-chunk sums + write gh x-half bf16 --------
__global__ void k_pre1(const float* __restrict__ x, float* __restrict__ chsum,
                       unsigned short* __restrict__ gh) {
  int bh = blockIdx.x, ch = blockIdx.y, d = threadIdx.x;
  int b = bh >> 3, h = bh & 7;
  float s = 0.0f;
  for (int i = 0; i < SC; ++i) {
    size_t mh = ((size_t)(b * S + ch * SC + i) * H + h);
    float xv = x[mh * D + d];
    gh[mh * 256 + d] = f2bu(xv);
    s += xv;
  }
  chsum[((size_t)bh * NCH + ch) * D + d] = s;
}

// ---------------- prefix phase 2: scan chunk sums ----------------
__global__ void k_pre2(const float* __restrict__ chsum, float* __restrict__ choff) {
  int bh = blockIdx.x, d = threadIdx.x;
  float a = 0.0f;
  for (int c = 0; c < NCH; ++c) {
    size_t idx = ((size_t)bh * NCH + c) * D + d;
    choff[idx] = a;
    a += chsum[idx];
  }
}

// ---------------- prefix phase 3: exclusive cumsum (from gh-x bf16) -> Pb ------
__global__ void k_pre3(const unsigned short* __restrict__ gh,
                       const float* __restrict__ choff,
                       __hip_bfloat16* __restrict__ P) {
  int bh = blockIdx.x, ch = blockIdx.y, d = threadIdx.x;
  int b = bh >> 3, h = bh & 7;
  float acc = choff[((size_t)bh * NCH + ch) * D + d];
  for (int i = 0; i < SC; ++i) {
    size_t mh = ((size_t)(b * S + ch * SC + i) * H + h);
    P[mh * D + d] = __float2bfloat16(acc);
    acc += b2f(gh[mh * 256 + d]);
  }
}

// ---------------- block stats helper (256 threads) ----------------
DEV void block_stats(float lsum, float lss, int n, float& mean, float& var) {
  #pragma unroll
  for (int o = 32; o > 0; o >>= 1) {
    lsum += __shfl_down(lsum, o);
    lss  += __shfl_down(lss, o);
  }
  __shared__ float wsum[4], wss[4];
  int wid = threadIdx.x >> 6;
  if ((threadIdx.x & 63) == 0) { wsum[wid] = lsum; wss[wid] = lss; }
  __syncthreads();
  float s = 0.0f, q = 0.0f;
  #pragma unroll
  for (int i = 0; i < 4; ++i) { s += wsum[i]; q += wss[i]; }
  mean = s / n;
  var = q / n - mean * mean;
}

// ---------------- csum LN over (H,D)=1024: Pb bf16 -> gh csum-half -------------
__global__ __launch_bounds__(256) void k_csum_ln(const __hip_bfloat16* __restrict__ P,
                                                 const float* __restrict__ g,
                                                 const float* __restrict__ bb,
                                                 unsigned short* __restrict__ gh) {
  size_t m = blockIdx.x;
  int t = threadIdx.x;
  ushort4 raw = ((const ushort4*)(P + m * 1024))[t];
  float v0 = b2f(raw.x), v1 = b2f(raw.y), v2 = b2f(raw.z), v3 = b2f(raw.w);
  float lsum = v0 + v1 + v2 + v3;
  float lss = v0 * v0 + v1 * v1 + v2 * v2 + v3 * v3;
  float mean, var;
  block_stats(lsum, lss, 1024, mean, var);
  float rs = rsqrtf(var + 1e-6f);
  float4 gv = *(const float4*)(g + t * 4);
  float4 bv = *(const float4*)(bb + t * 4);
  int h = t >> 5;
  int d0 = (t * 4) & 127;
  ushort4 o;
  o.x = f2bu((v0 - mean) * rs * gv.x + bv.x);
  o.y = f2bu((v1 - mean) * rs * gv.y + bv.y);
  o.z = f2bu((v2 - mean) * rs * gv.z + bv.z);
  o.w = f2bu((v3 - mean) * rs * gv.w + bv.w);
  *(ushort4*)(gh + (m * 8 + h) * 256 + 128 + d0) = o;
}

// ---------------- stats finalize: (sum, ss) -> (mean, rstd) --------------------
__global__ void k_finalize(const float* __restrict__ isum, const float* __restrict__ iss,
                           const float* __restrict__ hsum, const float* __restrict__ hss,
                           float2* __restrict__ ims, float2* __restrict__ hms) {
  int m = blockIdx.x * 256 + threadIdx.x;
  float mean = isum[m] / 2048.0f;
  float var = iss[m] / 2048.0f - mean * mean;
  ims[m] = float2{mean, rsqrtf(var + 1e-6f)};
  mean = hsum[m] / 4096.0f;
  var = hss[m] / 4096.0f - mean * mean;
  hms[m] = float2{mean, rsqrtf(var + 1e-6f)};
}

// ---------------- MFMA bf16 GEMM ----------------
// grid = NT*MT*8 (1D, XCD-grouped: r=bid&7 picks XCD; n-tiles of same (m,h)
// consecutive on one XCD so the A-slice is L2-resident).
// AKIND 0: A = Ab bf16 [M][H][K].
// AKIND 1: A = hid bf16 [M][H][512] with on-load LN(mean/rstd from Ams)+g,b+relu.
// AKIND 2: A = [gh-x (stride 256) | cell (stride 128)] bf16.
// EPI 0: bf16 store.  EPI 2: igh = sigmoid(LN(igate_raw)) * (acc+bias).
// STATS: epilogue row-stats atomics into st_sum/st_ss.
template <int BM_, int N, int K, int AKIND, int EPI, bool STATS>
__global__ __launch_bounds__(512) void k_mgemm(
    const __hip_bfloat16* __restrict__ Ab, const __hip_bfloat16* __restrict__ Ab2,
    const float2* __restrict__ Ams, const float* __restrict__ Ag,
    const float* __restrict__ Abeta,
    const __hip_bfloat16* __restrict__ Wt, const float* __restrict__ bias,
    __hip_bfloat16* __restrict__ out_b,
    const __hip_bfloat16* __restrict__ ifg_raw, const float2* __restrict__ ifg_ms,
    const float* __restrict__ ifg_gw, const float* __restrict__ ifg_bw,
    __hip_bfloat16* __restrict__ igh,
    float* __restrict__ st_sum, float* __restrict__ st_ss) {
  constexpr int BN = 128, BK = 32;
  constexpr int LDA = 40;           // bf16 stride: 2-way-max LDS bank aliasing
  constexpr int MT = M / BM_;
  constexpr int NT = N / BN;
  constexpr int MI = BM_ / 64;      // acc rows per wave / 16
  __shared__ __align__(16) short As[BM_ * LDA];
  __shared__ __align__(16) short Bs[BN * LDA];
  int bid = blockIdx.x;
  int r = bid & 7, q = bid >> 3;
  int p = q / NT, n = q % NT;
  int mh = r * MT + p;
  int m0 = (mh >> 3) * BM_;
  int h = mh & 7;
  int n0 = n * BN;
  int tid = threadIdx.x;
  int w = tid >> 6, lane = tid & 63;
  int wr = w >> 1, wc = w & 1;
  int l15 = lane & 15, l4 = lane >> 4;
  f32x4 acc[MI][4] = {};
  for (int kt = 0; kt < K; kt += BK) {
    // stage A: BM_ x 32 bf16
    #pragma unroll
    for (int rr = 0; rr < BM_ / 128; ++rr) {
      int qq = tid + rr * 512;
      int row = qq >> 2, cq = qq & 3;
      int kk = kt + cq * 8;
      int mg = m0 + row;
      short8 v;
      if (AKIND == 0) {
        v = *reinterpret_cast<const short8*>(Ab + ((size_t)mg * H + h) * K + kk);
      } else if (AKIND == 2) {
        if (kk < 128) v = *reinterpret_cast<const short8*>(Ab + ((size_t)mg * H + h) * 256 + kk);
        else          v = *reinterpret_cast<const short8*>(Ab2 + ((size_t)mg * H + h) * 128 + kk - 128);
      } else {  // AKIND 1: LN + relu on load
        short8 t0 = *reinterpret_cast<const short8*>(Ab + ((size_t)mg * H + h) * K + kk);
        float2 ms = Ams[mg];
        #pragma unroll
        for (int e = 0; e < 8; ++e) {
          float f = (b2f((unsigned short)t0[e]) - ms.x) * ms.y * Ag[h * K + kk + e]
                    + Abeta[h * K + kk + e];
          v[e] = (short)f2bu(f > 0.0f ? f : 0.0f);
        }
      }
      *reinterpret_cast<short8*>(As + row * LDA + cq * 8) = v;
    }
    // stage B: 128 x 32 bf16
    {
      int row = tid >> 2, cq = tid & 3;
      short8 v = *reinterpret_cast<const short8*>(
          Wt + ((size_t)h * N + n0 + row) * K + kt + cq * 8);
      *reinterpret_cast<short8*>(Bs + row * LDA + cq * 8) = v;
    }
    __syncthreads();
    short8 a[MI], bfr[4];
    #pragma unroll
    for (int i = 0; i < MI; ++i)
      a[i] = *reinterpret_cast<const short8*>(As + (wr * (MI * 16) + i * 16 + l15) * LDA + l4 * 8);
    #pragma unroll
    for (int j = 0; j < 4; ++j)
      bfr[j] = *reinterpret_cast<const short8*>(Bs + (wc * 64 + j * 16 + l15) * LDA + l4 * 8);
    #pragma unroll
    for (int i = 0; i < MI; ++i)
      #pragma unroll
      for (int j = 0; j < 4; ++j)
        acc[i][j] = __builtin_amdgcn_mfma_f32_16x16x32_bf16(a[i], bfr[j], acc[i][j], 0, 0, 0);
    __syncthreads();
  }
  // epilogue: C row = (lane>>4)*4 + reg, col = lane&15  [m89-verified]
  #pragma unroll
  for (int i = 0; i < MI; ++i) {
    #pragma unroll
    for (int rr2 = 0; rr2 < 4; ++rr2) {
      int mg = m0 + wr * (MI * 16) + i * 16 + l4 * 4 + rr2;
      size_t mhn = (size_t)mg * H + h;
      float lsum = 0.0f, lss = 0.0f;
      #pragma unroll
      for (int j = 0; j < 4; ++j) {
        int o = n0 + wc * 64 + j * 16 + l15;
        float v = acc[i][j][rr2] + bias[h * N + o];
        if (EPI == 0) {
          out_b[mhn * N + o] = __float2bfloat16(v);
        } else {  // EPI 2: igh = sigmoid(LN(igate)) * hidden   (N==128)
          float ig = b2f(*(const unsigned short*)(ifg_raw + mhn * 256 + o));
          float2 ms = ifg_ms[mg];
          float gi = sigmoidf_((ig - ms.x) * ms.y * ifg_gw[h * 256 + o] + ifg_bw[h * 256 + o]);
          igh[mhn * 128 + o] = __float2bfloat16(gi * v);
        }
        lsum += v; lss += v * v;
      }
      if constexpr (STATS) {
        #pragma unroll
        for (int ox = 8; ox > 0; ox >>= 1) {
          lsum += __shfl_xor(lsum, ox);
          lss  += __shfl_xor(lss, ox);
        }
        if (l15 == 0) {
          atomicAdd(&st_sum[mg], lsum);
          atomicAdd(&st_ss[mg], lss);
        }
      }
    }
  }
}

// ---------------- scan phase 1: per-chunk composed (F, I); LN+sigmoid inline ---
__global__ void k_scan1(const __hip_bfloat16* __restrict__ ifg_raw,
                        const float2* __restrict__ ms_arr,
                        const float* __restrict__ ifg_gw, const float* __restrict__ ifg_bw,
                        const __hip_bfloat16* __restrict__ igh,
                        float* __restrict__ chF, float* __restrict__ chI) {
  int bh = blockIdx.x, ch = blockIdx.y, d = threadIdx.x;
  int b = bh >> 3, h = bh & 7;
  float gw = ifg_gw[h * 256 + 128 + d], gb = ifg_bw[h * 256 + 128 + d];
  float F = 1.0f, Iv = 0.0f;
  int mb = b * S + ch * SC;
  for (int i = 0; i < SC; ++i) {
    int m = mb + i;
    size_t mh = (size_t)m * H + h;
    float2 ms = ms_arr[m];
    float f = sigmoidf_((b2f(*(const unsigned short*)(ifg_raw + mh * 256 + 128 + d)) - ms.x) * ms.y * gw + gb);
    float iv = b2f(*(const unsigned short*)(igh + mh * 128 + d));
    F *= f;
    Iv = f * Iv + iv;
  }
  size_t idx = ((size_t)bh * NCH + ch) * D + d;
  chF[idx] = F;
  chI[idx] = Iv;
}

// ---------------- scan phase 2: chunk-start cells ----------------
__global__ void k_scan2(const float* __restrict__ chF, const float* __restrict__ chI,
                        const float* __restrict__ init_cx, float* __restrict__ cst) {
  int bh = blockIdx.x, d = threadIdx.x;
  int h = bh & 7;
  float c = init_cx[h * D + d];
  for (int ch = 0; ch < NCH; ++ch) {
    size_t idx = ((size_t)bh * NCH + ch) * D + d;
    cst[idx] = c;
    c = chF[idx] * c + chI[idx];
  }
}

// ---------------- scan phase 3: re-scan chunk, write cell bf16 -----------------
__global__ void k_scan3(const __hip_bfloat16* __restrict__ ifg_raw,
                        const float2* __restrict__ ms_arr,
                        const float* __restrict__ ifg_gw, const float* __restrict__ ifg_bw,
                        const __hip_bfloat16* __restrict__ igh,
                        const float* __restrict__ cst,
                        __hip_bfloat16* __restrict__ cell) {
  int bh = blockIdx.x, ch = blockIdx.y, d = threadIdx.x;
  int b = bh >> 3, h = bh & 7;
  float gw = ifg_gw[h * 256 + 128 + d], gb = ifg_bw[h * 256 + 128 + d];
  float c = cst[((size_t)bh * NCH + ch) * D + d];
  int mb = b * S + ch * SC;
  for (int i = 0; i < SC; ++i) {
    int m = mb + i;
    size_t mh = (size_t)m * H + h;
    float2 ms = ms_arr[m];
    float f = sigmoidf_((b2f(*(const unsigned short*)(ifg_raw + mh * 256 + 128 + d)) - ms.x) * ms.y * gw + gb);
    float iv = b2f(*(const unsigned short*)(igh + mh * 128 + d));
    c = f * c + iv;
    cell[mh * 128 + d] = __float2bfloat16(c);
  }
}

// ---------------- og LN over (H,D)=1024, sigmoid, * cell -> out f32 ------------
__global__ __launch_bounds__(256) void k_og_out(const __hip_bfloat16* __restrict__ og,
                                                const __hip_bfloat16* __restrict__ cell,
                                                const float* __restrict__ g,
                                                const float* __restrict__ bb,
                                                float* __restrict__ out) {
  size_t m = blockIdx.x;
  int t = threadIdx.x;
  ushort4 raw = ((const ushort4*)(og + m * 1024))[t];
  float v0 = b2f(raw.x), v1 = b2f(raw.y), v2 = b2f(raw.z), v3 = b2f(raw.w);
  float lsum = v0 + v1 + v2 + v3;
  float lss = v0 * v0 + v1 * v1 + v2 * v2 + v3 * v3;
  float mean, var;
  block_stats(lsum, lss, 1024, mean, var);
  float rs = rsqrtf(var + 1e-6f);
  float4 gv = *(const float4*)(g + t * 4);
  float4 bv = *(const float4*)(bb + t * 4);
  ushort4 cv = ((const ushort4*)(cell + m * 1024))[t];
  float4 o;
  o.x = sigmoidf_((v0 - mean) * rs * gv.x + bv.x) * b2f(cv.x);
  o.y = sigmoidf_((v1 - mean) * rs * gv.y + bv.y) * b2f(cv.y);
  o.z = sigmoidf_((v2 - mean) * rs * gv.z + bv.z) * b2f(cv.z);
  o.w = sigmoidf_((v3 - mean) * rs * gv.w + bv.w) * b2f(cv.w);
  ((float4*)(out + m * 1024))[t] = o;
}

extern "C" void kernel_launch(void* const* d_in, const int* in_sizes, int n_in,
                              void* d_out, int out_size, void* d_ws, size_t ws_size,
                              hipStream_t stream) {
  (void)in_sizes; (void)n_in; (void)out_size; (void)ws_size;
  const float* x       = (const float*)d_in[0];
  const float* W_ifg   = (const float*)d_in[1];
  const float* b_ifg   = (const float*)d_in[2];
  const float* W_hid1  = (const float*)d_in[3];
  const float* b_hid1  = (const float*)d_in[4];
  const float* hid_g   = (const float*)d_in[5];
  const float* hid_b   = (const float*)d_in[6];
  const float* W_hid2  = (const float*)d_in[7];
  const float* b_hid2  = (const float*)d_in[8];
  const float* W_og    = (const float*)d_in[9];
  const float* b_og    = (const float*)d_in[10];
  const float* og_g    = (const float*)d_in[11];
  const float* og_b    = (const float*)d_in[12];
  const float* csum_g  = (const float*)d_in[13];
  const float* csum_b  = (const float*)d_in[14];
  const float* ifg_g   = (const float*)d_in[15];
  const float* ifg_b   = (const float*)d_in[16];
  const float* init_cx = (const float*)d_in[17];
  float* out = (float*)d_out;

  // ---- workspace map (bytes; peak ~157.6 MB) ----
  // [0,32M):        gh bf16 [M][H][256]        (pre1 -> og gemm)
  // [32M,64M):      ifg raw bf16 (ifg gemm -> scan3); og bf16 reuses (og gemm ->)
  // [64M,128M):     hid bf16 (hid1 -> hid2);  cell bf16 reuses (scan3 -> og_out)
  // [128M,144M):    Pb bf16 (pre3 -> csum_ln); igh bf16 reuses (hid2 -> scan3)
  // [144M,...):     weights bf16, scan bufs, stats
  char* w = (char*)d_ws;
  unsigned short* gh     = (unsigned short*)w;
  __hip_bfloat16* ghb    = (__hip_bfloat16*)w;
  __hip_bfloat16* ifg    = (__hip_bfloat16*)(w + 33554432);
  __hip_bfloat16* og     = (__hip_bfloat16*)(w + 33554432);
  __hip_bfloat16* hid    = (__hip_bfloat16*)(w + 67108864);
  __hip_bfloat16* cell   = (__hip_bfloat16*)(w + 67108864);
  __hip_bfloat16* Pb     = (__hip_bfloat16*)(w + 134217728);
  __hip_bfloat16* igh    = (__hip_bfloat16*)(w + 134217728);
  __hip_bfloat16* wt_ifg = (__hip_bfloat16*)(w + 150994944);
  __hip_bfloat16* wt_h1  = (__hip_bfloat16*)(w + 152043520);
  __hip_bfloat16* wt_h2  = (__hip_bfloat16*)(w + 154140672);
  __hip_bfloat16* wt_og  = (__hip_bfloat16*)(w + 155189248);
  float* chsum           = (float*)(w + 155713536);  // also chF
  float* choff           = (float*)(w + 156237824);  // also chI
  float* cst             = (float*)(w + 156762112);
  float* ifg_sum         = (float*)(w + 157286400);  // 32 KB
  float* ifg_ss          = (float*)(w + 157319168);
  float* hid_sum         = (float*)(w + 157351936);
  float* hid_ss          = (float*)(w + 157384704);
  float2* ifg_ms         = (float2*)(w + 157417472); // 64 KB
  float2* hid_ms         = (float2*)(w + 157483008); // ends 157548544
  float* chF = chsum;
  float* chI = choff;

  // 0. zero stats (ws is poisoned every launch)
  k_zero<<<dim3(32), dim3(256), 0, stream>>>((float4*)ifg_sum);

  // 1. one-off weight transpose+bf16
  k_wcvt<<<dim3(8, 8, 8),  dim3(32, 8), 0, stream>>>(W_ifg,  wt_ifg, 256, 256);
  k_wcvt<<<dim3(8, 16, 8), dim3(32, 8), 0, stream>>>(W_hid1, wt_h1,  256, 512);
  k_wcvt<<<dim3(16, 4, 8), dim3(32, 8), 0, stream>>>(W_hid2, wt_h2,  512, 128);
  k_wcvt<<<dim3(8, 4, 8),  dim3(32, 8), 0, stream>>>(W_og,   wt_og,  256, 128);

  // 2-3. chunked exclusive prefix sum -> Pb; LN -> gh csum-half
  k_pre1<<<dim3(32, NCH), dim3(D), 0, stream>>>(x, chsum, gh);
  k_pre2<<<dim3(32), dim3(D), 0, stream>>>(chsum, choff);
  k_pre3<<<dim3(32, NCH), dim3(D), 0, stream>>>(gh, choff, Pb);
  k_csum_ln<<<dim3(M), dim3(256), 0, stream>>>(Pb, csum_g, csum_b, gh);

  // 4-5. wide GEMMs (A = gh bf16) with epilogue row-stats
  k_mgemm<256, 256, 256, 0, 0, true><<<dim3(512), dim3(512), 0, stream>>>(
      ghb, nullptr, nullptr, nullptr, nullptr, wt_ifg, b_ifg, ifg,
      nullptr, nullptr, nullptr, nullptr, nullptr, ifg_sum, ifg_ss);
  k_mgemm<256, 512, 256, 0, 0, true><<<dim3(1024), dim3(512), 0, stream>>>(
      ghb, nullptr, nullptr, nullptr, nullptr, wt_h1, b_hid1, hid,
      nullptr, nullptr, nullptr, nullptr, nullptr, hid_sum, hid_ss);

  // 6. finalize LN stats
  k_finalize<<<dim3(32), dim3(256), 0, stream>>>(
      ifg_sum, ifg_ss, hid_sum, hid_ss, ifg_ms, hid_ms);

  // 7. hid2 GEMM: A = LN+relu(hid) on load; epilogue igh = sigmoid(LN(ig))*hidden
  k_mgemm<128, 128, 512, 1, 2, false><<<dim3(512), dim3(512), 0, stream>>>(
      hid, nullptr, hid_ms, hid_g, hid_b, wt_h2, b_hid2, nullptr,
      ifg, ifg_ms, ifg_g, ifg_b, igh, nullptr, nullptr);

  // 8-10. chunked LSTM scan (LN+sigmoid of fgate inline)
  k_scan1<<<dim3(32, NCH), dim3(D), 0, stream>>>(ifg, ifg_ms, ifg_g, ifg_b, igh, chF, chI);
  k_scan2<<<dim3(32), dim3(D), 0, stream>>>(chF, chI, init_cx, cst);
  k_scan3<<<dim3(32, NCH), dim3(D), 0, stream>>>(ifg, ifg_ms, ifg_g, ifg_b, igh, cst, cell);

  // 11-12. og GEMM (A = [gh-x | cell] bf16) + final output
  k_mgemm<128, 128, 256, 2, 0, false><<<dim3(512), dim3(512), 0, stream>>>(
      ghb, cell, nullptr, nullptr, nullptr, wt_og, b_og, og,
      nullptr, nullptr, nullptr, nullptr, nullptr, nullptr, nullptr);
  k_og_out<<<dim3(M), dim3(256), 0, stream>>>(og, cell, og_g, og_b, out);
}

// Round 7
// 356.237 us; speedup vs baseline: 1.0792x; 1.0792x over previous
//
#include <hip/hip_runtime.h>
#include <hip/hip_bf16.h>

#define DEV static __device__ __forceinline__

constexpr int B = 4, S = 2048, H = 8, D = 128, FH = 512;
constexpr int M = B * S;   // 8192
constexpr int SC = 64;     // scan/prefix chunk length
constexpr int NCH = S / SC; // 32

typedef __attribute__((ext_vector_type(8))) short short8;
typedef __attribute__((ext_vector_type(4))) float f32x4;

DEV float sigmoidf_(float x) { return 1.0f / (1.0f + __expf(-x)); }
DEV float b2f(unsigned short u) { union { unsigned int i; float f; } x; x.i = (unsigned int)u << 16; return x.f; }
DEV unsigned short f2bu(float f) { __hip_bfloat16 b = __float2bfloat16(f); union { __hip_bfloat16 b; unsigned short u; } x; x.b = b; return x.u; }

// ---------------- zero stats buffers (re-poisoned to 0xAA every launch) --------
__global__ void k_zero(float4* __restrict__ p) {
  p[blockIdx.x * 256 + threadIdx.x] = float4{0.f, 0.f, 0.f, 0.f};
}

// ---------------- weight convert + transpose: W[h][k][n] f32 -> Wt[h][n][k] bf16
__global__ void k_wcvt(const float* __restrict__ W, __hip_bfloat16* __restrict__ Wt,
                       int K, int N) {
  __shared__ float t[32][33];
  int h = blockIdx.z;
  int k0 = blockIdx.x * 32, n0 = blockIdx.y * 32;
  int tx = threadIdx.x, ty = threadIdx.y;  // 32 x 8
  #pragma unroll
  for (int r = 0; r < 32; r += 8)
    t[ty + r][tx] = W[((size_t)h * K + k0 + ty + r) * N + n0 + tx];
  __syncthreads();
  #pragma unroll
  for (int r = 0; r < 32; r += 8)
    Wt[((size_t)h * N + n0 + ty + r) * K + k0 + tx] = __float2bfloat16(t[tx][ty + r]);
}

// ---------------- prefix phase 1: per-chunk sums + write gh x-half bf16 --------
__global__ void k_pre1(const float* __restrict__ x, float* __restrict__ chsum,
                       unsigned short* __restrict__ gh) {
  int bh = blockIdx.x, ch = blockIdx.y, d = threadIdx.x;
  int b = bh >> 3, h = bh & 7;
  float s = 0.0f;
  for (int i = 0; i < SC; ++i) {
    size_t mh = ((size_t)(b * S + ch * SC + i) * H + h);
    float xv = x[mh * D + d];
    gh[mh * 256 + d] = f2bu(xv);
    s += xv;
  }
  chsum[((size_t)bh * NCH + ch) * D + d] = s;
}

// ---------------- prefix phase 2: scan chunk sums ----------------
__global__ void k_pre2(const float* __restrict__ chsum, float* __restrict__ choff) {
  int bh = blockIdx.x, d = threadIdx.x;
  float a = 0.0f;
  for (int c = 0; c < NCH; ++c) {
    size_t idx = ((size_t)bh * NCH + c) * D + d;
    choff[idx] = a;
    a += chsum[idx];
  }
}

// ---------------- prefix phase 3: exclusive cumsum (from gh-x bf16) -> Pb ------
__global__ void k_pre3(const unsigned short* __restrict__ gh,
                       const float* __restrict__ choff,
                       __hip_bfloat16* __restrict__ P) {
  int bh = blockIdx.x, ch = blockIdx.y, d = threadIdx.x;
  int b = bh >> 3, h = bh & 7;
  float acc = choff[((size_t)bh * NCH + ch) * D + d];
  for (int i = 0; i < SC; ++i) {
    size_t mh = ((size_t)(b * S + ch * SC + i) * H + h);
    P[mh * D + d] = __float2bfloat16(acc);
    acc += b2f(gh[mh * 256 + d]);
  }
}

// ---------------- block stats helper (256 threads) ----------------
DEV void block_stats(float lsum, float lss, int n, float& mean, float& var) {
  #pragma unroll
  for (int o = 32; o > 0; o >>= 1) {
    lsum += __shfl_down(lsum, o);
    lss  += __shfl_down(lss, o);
  }
  __shared__ float wsum[4], wss[4];
  int wid = threadIdx.x >> 6;
  if ((threadIdx.x & 63) == 0) { wsum[wid] = lsum; wss[wid] = lss; }
  __syncthreads();
  float s = 0.0f, q = 0.0f;
  #pragma unroll
  for (int i = 0; i < 4; ++i) { s += wsum[i]; q += wss[i]; }
  mean = s / n;
  var = q / n - mean * mean;
}

// ---------------- csum LN over (H,D)=1024: Pb bf16 -> gh csum-half -------------
__global__ __launch_bounds__(256) void k_csum_ln(const __hip_bfloat16* __restrict__ P,
                                                 const float* __restrict__ g,
                                                 const float* __restrict__ bb,
                                                 unsigned short* __restrict__ gh) {
  size_t m = blockIdx.x;
  int t = threadIdx.x;
  ushort4 raw = ((const ushort4*)(P + m * 1024))[t];
  float v0 = b2f(raw.x), v1 = b2f(raw.y), v2 = b2f(raw.z), v3 = b2f(raw.w);
  float lsum = v0 + v1 + v2 + v3;
  float lss = v0 * v0 + v1 * v1 + v2 * v2 + v3 * v3;
  float mean, var;
  block_stats(lsum, lss, 1024, mean, var);
  float rs = rsqrtf(var + 1e-6f);
  float4 gv = *(const float4*)(g + t * 4);
  float4 bv = *(const float4*)(bb + t * 4);
  int h = t >> 5;
  int d0 = (t * 4) & 127;
  ushort4 o;
  o.x = f2bu((v0 - mean) * rs * gv.x + bv.x);
  o.y = f2bu((v1 - mean) * rs * gv.y + bv.y);
  o.z = f2bu((v2 - mean) * rs * gv.z + bv.z);
  o.w = f2bu((v3 - mean) * rs * gv.w + bv.w);
  *(ushort4*)(gh + (m * 8 + h) * 256 + 128 + d0) = o;
}

// ---------------- stats finalize: (sum, ss) -> (mean, rstd) --------------------
__global__ void k_finalize(const float* __restrict__ isum, const float* __restrict__ iss,
                           const float* __restrict__ hsum, const float* __restrict__ hss,
                           float2* __restrict__ ims, float2* __restrict__ hms) {
  int m = blockIdx.x * 256 + threadIdx.x;
  float mean = isum[m] / 2048.0f;
  float var = iss[m] / 2048.0f - mean * mean;
  ims[m] = float2{mean, rsqrtf(var + 1e-6f)};
  mean = hsum[m] / 4096.0f;
  var = hss[m] / 4096.0f - mean * mean;
  hms[m] = float2{mean, rsqrtf(var + 1e-6f)};
}

// ---------------- MFMA bf16 GEMM ----------------
// grid = NT*MT*8 (1D, XCD-grouped: r=bid&7 picks XCD; n-tiles of same (m,h)
// consecutive on one XCD so the A-slice is L2-resident).
// __launch_bounds__(512, 4): 4 waves/EU = 2 blocks/CU; forces VGPR+AGPR <= 128
// (round-6 lesson: 68 VGPR + 64 AGPR = 132 crossed the 128 cliff -> 1 block/CU,
//  2x slowdown; acc is 64 AGPR so the VALU side must stay <= 64).
// AKIND 0: A = Ab bf16 [M][H][K].
// AKIND 1: A = hid bf16 [M][H][512] with on-load LN(mean/rstd from Ams)+g,b+relu.
// AKIND 2: A = [gh-x (stride 256) | cell (stride 128)] bf16.
// EPI 0: bf16 store.  EPI 2: igh = sigmoid(LN(igate_raw)) * (acc+bias).
// STATS: epilogue row-stats atomics into st_sum/st_ss.
template <int BM_, int N, int K, int AKIND, int EPI, bool STATS>
__global__ __launch_bounds__(512, 4) void k_mgemm(
    const __hip_bfloat16* __restrict__ Ab, const __hip_bfloat16* __restrict__ Ab2,
    const float2* __restrict__ Ams, const float* __restrict__ Ag,
    const float* __restrict__ Abeta,
    const __hip_bfloat16* __restrict__ Wt, const float* __restrict__ bias,
    __hip_bfloat16* __restrict__ out_b,
    const __hip_bfloat16* __restrict__ ifg_raw, const float2* __restrict__ ifg_ms,
    const float* __restrict__ ifg_gw, const float* __restrict__ ifg_bw,
    __hip_bfloat16* __restrict__ igh,
    float* __restrict__ st_sum, float* __restrict__ st_ss) {
  constexpr int BN = 128, BK = 32;
  constexpr int LDA = 40;           // bf16 stride: 2-way-max LDS bank aliasing
  constexpr int MT = M / BM_;
  constexpr int NT = N / BN;
  constexpr int MI = BM_ / 64;      // acc rows per wave / 16
  __shared__ __align__(16) short As[BM_ * LDA];
  __shared__ __align__(16) short Bs[BN * LDA];
  int bid = blockIdx.x;
  int r = bid & 7, q = bid >> 3;
  int p = q / NT, n = q % NT;
  int mh = r * MT + p;
  int m0 = (mh >> 3) * BM_;
  int h = mh & 7;
  int n0 = n * BN;
  int tid = threadIdx.x;
  int w = tid >> 6, lane = tid & 63;
  int wr = w >> 1, wc = w & 1;
  int l15 = lane & 15, l4 = lane >> 4;
  f32x4 acc[MI][4] = {};
  for (int kt = 0; kt < K; kt += BK) {
    // stage A: BM_ x 32 bf16
    #pragma unroll
    for (int rr = 0; rr < BM_ / 128; ++rr) {
      int qq = tid + rr * 512;
      int row = qq >> 2, cq = qq & 3;
      int kk = kt + cq * 8;
      int mg = m0 + row;
      short8 v;
      if (AKIND == 0) {
        v = *reinterpret_cast<const short8*>(Ab + ((size_t)mg * H + h) * K + kk);
      } else if (AKIND == 2) {
        if (kk < 128) v = *reinterpret_cast<const short8*>(Ab + ((size_t)mg * H + h) * 256 + kk);
        else          v = *reinterpret_cast<const short8*>(Ab2 + ((size_t)mg * H + h) * 128 + kk - 128);
      } else {  // AKIND 1: LN + relu on load
        short8 t0 = *reinterpret_cast<const short8*>(Ab + ((size_t)mg * H + h) * K + kk);
        float2 ms = Ams[mg];
        #pragma unroll
        for (int e = 0; e < 8; ++e) {
          float f = (b2f((unsigned short)t0[e]) - ms.x) * ms.y * Ag[h * K + kk + e]
                    + Abeta[h * K + kk + e];
          v[e] = (short)f2bu(f > 0.0f ? f : 0.0f);
        }
      }
      *reinterpret_cast<short8*>(As + row * LDA + cq * 8) = v;
    }
    // stage B: 128 x 32 bf16
    {
      int row = tid >> 2, cq = tid & 3;
      short8 v = *reinterpret_cast<const short8*>(
          Wt + ((size_t)h * N + n0 + row) * K + kt + cq * 8);
      *reinterpret_cast<short8*>(Bs + row * LDA + cq * 8) = v;
    }
    __syncthreads();
    short8 a[MI], bfr[4];
    #pragma unroll
    for (int i = 0; i < MI; ++i)
      a[i] = *reinterpret_cast<const short8*>(As + (wr * (MI * 16) + i * 16 + l15) * LDA + l4 * 8);
    #pragma unroll
    for (int j = 0; j < 4; ++j)
      bfr[j] = *reinterpret_cast<const short8*>(Bs + (wc * 64 + j * 16 + l15) * LDA + l4 * 8);
    #pragma unroll
    for (int i = 0; i < MI; ++i)
      #pragma unroll
      for (int j = 0; j < 4; ++j)
        acc[i][j] = __builtin_amdgcn_mfma_f32_16x16x32_bf16(a[i], bfr[j], acc[i][j], 0, 0, 0);
    __syncthreads();
  }
  // epilogue: C row = (lane>>4)*4 + reg, col = lane&15  [m89-verified]
  #pragma unroll
  for (int i = 0; i < MI; ++i) {
    #pragma unroll
    for (int rr2 = 0; rr2 < 4; ++rr2) {
      int mg = m0 + wr * (MI * 16) + i * 16 + l4 * 4 + rr2;
      size_t mhn = (size_t)mg * H + h;
      float lsum = 0.0f, lss = 0.0f;
      #pragma unroll
      for (int j = 0; j < 4; ++j) {
        int o = n0 + wc * 64 + j * 16 + l15;
        float v = acc[i][j][rr2] + bias[h * N + o];
        if (EPI == 0) {
          out_b[mhn * N + o] = __float2bfloat16(v);
        } else {  // EPI 2: igh = sigmoid(LN(igate)) * hidden   (N==128)
          float ig = b2f(*(const unsigned short*)(ifg_raw + mhn * 256 + o));
          float2 ms = ifg_ms[mg];
          float gi = sigmoidf_((ig - ms.x) * ms.y * ifg_gw[h * 256 + o] + ifg_bw[h * 256 + o]);
          igh[mhn * 128 + o] = __float2bfloat16(gi * v);
        }
        lsum += v; lss += v * v;
      }
      if constexpr (STATS) {
        #pragma unroll
        for (int ox = 8; ox > 0; ox >>= 1) {
          lsum += __shfl_xor(lsum, ox);
          lss  += __shfl_xor(lss, ox);
        }
        if (l15 == 0) {
          atomicAdd(&st_sum[mg], lsum);
          atomicAdd(&st_ss[mg], lss);
        }
      }
    }
  }
}

// ---------------- scan phase 1: per-chunk composed (F, I); LN+sigmoid inline ---
__global__ void k_scan1(const __hip_bfloat16* __restrict__ ifg_raw,
                        const float2* __restrict__ ms_arr,
                        const float* __restrict__ ifg_gw, const float* __restrict__ ifg_bw,
                        const __hip_bfloat16* __restrict__ igh,
                        float* __restrict__ chF, float* __restrict__ chI) {
  int bh = blockIdx.x, ch = blockIdx.y, d = threadIdx.x;
  int b = bh >> 3, h = bh & 7;
  float gw = ifg_gw[h * 256 + 128 + d], gb = ifg_bw[h * 256 + 128 + d];
  float F = 1.0f, Iv = 0.0f;
  int mb = b * S + ch * SC;
  for (int i = 0; i < SC; ++i) {
    int m = mb + i;
    size_t mh = (size_t)m * H + h;
    float2 ms = ms_arr[m];
    float f = sigmoidf_((b2f(*(const unsigned short*)(ifg_raw + mh * 256 + 128 + d)) - ms.x) * ms.y * gw + gb);
    float iv = b2f(*(const unsigned short*)(igh + mh * 128 + d));
    F *= f;
    Iv = f * Iv + iv;
  }
  size_t idx = ((size_t)bh * NCH + ch) * D + d;
  chF[idx] = F;
  chI[idx] = Iv;
}

// ---------------- scan phase 2: chunk-start cells ----------------
__global__ void k_scan2(const float* __restrict__ chF, const float* __restrict__ chI,
                        const float* __restrict__ init_cx, float* __restrict__ cst) {
  int bh = blockIdx.x, d = threadIdx.x;
  int h = bh & 7;
  float c = init_cx[h * D + d];
  for (int ch = 0; ch < NCH; ++ch) {
    size_t idx = ((size_t)bh * NCH + ch) * D + d;
    cst[idx] = c;
    c = chF[idx] * c + chI[idx];
  }
}

// ---------------- scan phase 3: re-scan chunk, write cell bf16 -----------------
__global__ void k_scan3(const __hip_bfloat16* __restrict__ ifg_raw,
                        const float2* __restrict__ ms_arr,
                        const float* __restrict__ ifg_gw, const float* __restrict__ ifg_bw,
                        const __hip_bfloat16* __restrict__ igh,
                        const float* __restrict__ cst,
                        __hip_bfloat16* __restrict__ cell) {
  int bh = blockIdx.x, ch = blockIdx.y, d = threadIdx.x;
  int b = bh >> 3, h = bh & 7;
  float gw = ifg_gw[h * 256 + 128 + d], gb = ifg_bw[h * 256 + 128 + d];
  float c = cst[((size_t)bh * NCH + ch) * D + d];
  int mb = b * S + ch * SC;
  for (int i = 0; i < SC; ++i) {
    int m = mb + i;
    size_t mh = (size_t)m * H + h;
    float2 ms = ms_arr[m];
    float f = sigmoidf_((b2f(*(const unsigned short*)(ifg_raw + mh * 256 + 128 + d)) - ms.x) * ms.y * gw + gb);
    float iv = b2f(*(const unsigned short*)(igh + mh * 128 + d));
    c = f * c + iv;
    cell[mh * 128 + d] = __float2bfloat16(c);
  }
}

// ---------------- og LN over (H,D)=1024, sigmoid, * cell -> out f32 ------------
__global__ __launch_bounds__(256) void k_og_out(const __hip_bfloat16* __restrict__ og,
                                                const __hip_bfloat16* __restrict__ cell,
                                                const float* __restrict__ g,
                                                const float* __restrict__ bb,
                                                float* __restrict__ out) {
  size_t m = blockIdx.x;
  int t = threadIdx.x;
  ushort4 raw = ((const ushort4*)(og + m * 1024))[t];
  float v0 = b2f(raw.x), v1 = b2f(raw.y), v2 = b2f(raw.z), v3 = b2f(raw.w);
  float lsum = v0 + v1 + v2 + v3;
  float lss = v0 * v0 + v1 * v1 + v2 * v2 + v3 * v3;
  float mean, var;
  block_stats(lsum, lss, 1024, mean, var);
  float rs = rsqrtf(var + 1e-6f);
  float4 gv = *(const float4*)(g + t * 4);
  float4 bv = *(const float4*)(bb + t * 4);
  ushort4 cv = ((const ushort4*)(cell + m * 1024))[t];
  float4 o;
  o.x = sigmoidf_((v0 - mean) * rs * gv.x + bv.x) * b2f(cv.x);
  o.y = sigmoidf_((v1 - mean) * rs * gv.y + bv.y) * b2f(cv.y);
  o.z = sigmoidf_((v2 - mean) * rs * gv.z + bv.z) * b2f(cv.z);
  o.w = sigmoidf_((v3 - mean) * rs * gv.w + bv.w) * b2f(cv.w);
  ((float4*)(out + m * 1024))[t] = o;
}

extern "C" void kernel_launch(void* const* d_in, const int* in_sizes, int n_in,
                              void* d_out, int out_size, void* d_ws, size_t ws_size,
                              hipStream_t stream) {
  (void)in_sizes; (void)n_in; (void)out_size; (void)ws_size;
  const float* x       = (const float*)d_in[0];
  const float* W_ifg   = (const float*)d_in[1];
  const float* b_ifg   = (const float*)d_in[2];
  const float* W_hid1  = (const float*)d_in[3];
  const float* b_hid1  = (const float*)d_in[4];
  const float* hid_g   = (const float*)d_in[5];
  const float* hid_b   = (const float*)d_in[6];
  const float* W_hid2  = (const float*)d_in[7];
  const float* b_hid2  = (const float*)d_in[8];
  const float* W_og    = (const float*)d_in[9];
  const float* b_og    = (const float*)d_in[10];
  const float* og_g    = (const float*)d_in[11];
  const float* og_b    = (const float*)d_in[12];
  const float* csum_g  = (const float*)d_in[13];
  const float* csum_b  = (const float*)d_in[14];
  const float* ifg_g   = (const float*)d_in[15];
  const float* ifg_b   = (const float*)d_in[16];
  const float* init_cx = (const float*)d_in[17];
  float* out = (float*)d_out;

  // ---- workspace map (bytes; peak ~157.6 MB) ----
  // [0,32M):        gh bf16 [M][H][256]        (pre1 -> og gemm)
  // [32M,64M):      ifg raw bf16 (ifg gemm -> scan3); og bf16 reuses (og gemm ->)
  // [64M,128M):     hid bf16 (hid1 -> hid2);  cell bf16 reuses (scan3 -> og_out)
  // [128M,144M):    Pb bf16 (pre3 -> csum_ln); igh bf16 reuses (hid2 -> scan3)
  // [144M,...):     weights bf16, scan bufs, stats
  char* w = (char*)d_ws;
  unsigned short* gh     = (unsigned short*)w;
  __hip_bfloat16* ghb    = (__hip_bfloat16*)w;
  __hip_bfloat16* ifg    = (__hip_bfloat16*)(w + 33554432);
  __hip_bfloat16* og     = (__hip_bfloat16*)(w + 33554432);
  __hip_bfloat16* hid    = (__hip_bfloat16*)(w + 67108864);
  __hip_bfloat16* cell   = (__hip_bfloat16*)(w + 67108864);
  __hip_bfloat16* Pb     = (__hip_bfloat16*)(w + 134217728);
  __hip_bfloat16* igh    = (__hip_bfloat16*)(w + 134217728);
  __hip_bfloat16* wt_ifg = (__hip_bfloat16*)(w + 150994944);
  __hip_bfloat16* wt_h1  = (__hip_bfloat16*)(w + 152043520);
  __hip_bfloat16* wt_h2  = (__hip_bfloat16*)(w + 154140672);
  __hip_bfloat16* wt_og  = (__hip_bfloat16*)(w + 155189248);
  float* chsum           = (float*)(w + 155713536);  // also chF
  float* choff           = (float*)(w + 156237824);  // also chI
  float* cst             = (float*)(w + 156762112);
  float* ifg_sum         = (float*)(w + 157286400);  // 32 KB
  float* ifg_ss          = (float*)(w + 157319168);
  float* hid_sum         = (float*)(w + 157351936);
  float* hid_ss          = (float*)(w + 157384704);
  float2* ifg_ms         = (float2*)(w + 157417472); // 64 KB
  float2* hid_ms         = (float2*)(w + 157483008); // ends 157548544
  float* chF = chsum;
  float* chI = choff;

  // 0. zero stats (ws is poisoned every launch)
  k_zero<<<dim3(32), dim3(256), 0, stream>>>((float4*)ifg_sum);

  // 1. one-off weight transpose+bf16
  k_wcvt<<<dim3(8, 8, 8),  dim3(32, 8), 0, stream>>>(W_ifg,  wt_ifg, 256, 256);
  k_wcvt<<<dim3(8, 16, 8), dim3(32, 8), 0, stream>>>(W_hid1, wt_h1,  256, 512);
  k_wcvt<<<dim3(16, 4, 8), dim3(32, 8), 0, stream>>>(W_hid2, wt_h2,  512, 128);
  k_wcvt<<<dim3(8, 4, 8),  dim3(32, 8), 0, stream>>>(W_og,   wt_og,  256, 128);

  // 2-3. chunked exclusive prefix sum -> Pb; LN -> gh csum-half
  k_pre1<<<dim3(32, NCH), dim3(D), 0, stream>>>(x, chsum, gh);
  k_pre2<<<dim3(32), dim3(D), 0, stream>>>(chsum, choff);
  k_pre3<<<dim3(32, NCH), dim3(D), 0, stream>>>(gh, choff, Pb);
  k_csum_ln<<<dim3(M), dim3(256), 0, stream>>>(Pb, csum_g, csum_b, gh);

  // 4-5. wide GEMMs (A = gh bf16) with epilogue row-stats
  k_mgemm<256, 256, 256, 0, 0, true><<<dim3(512), dim3(512), 0, stream>>>(
      ghb, nullptr, nullptr, nullptr, nullptr, wt_ifg, b_ifg, ifg,
      nullptr, nullptr, nullptr, nullptr, nullptr, ifg_sum, ifg_ss);
  k_mgemm<256, 512, 256, 0, 0, true><<<dim3(1024), dim3(512), 0, stream>>>(
      ghb, nullptr, nullptr, nullptr, nullptr, wt_h1, b_hid1, hid,
      nullptr, nullptr, nullptr, nullptr, nullptr, hid_sum, hid_ss);

  // 6. finalize LN stats
  k_finalize<<<dim3(32), dim3(256), 0, stream>>>(
      ifg_sum, ifg_ss, hid_sum, hid_ss, ifg_ms, hid_ms);

  // 7. hid2 GEMM: A = LN+relu(hid) on load; epilogue igh = sigmoid(LN(ig))*hidden
  k_mgemm<128, 128, 512, 1, 2, false><<<dim3(512), dim3(512), 0, stream>>>(
      hid, nullptr, hid_ms, hid_g, hid_b, wt_h2, b_hid2, nullptr,
      ifg, ifg_ms, ifg_g, ifg_b, igh, nullptr, nullptr);

  // 8-10. chunked LSTM scan (LN+sigmoid of fgate inline)
  k_scan1<<<dim3(32, NCH), dim3(D), 0, stream>>>(ifg, ifg_ms, ifg_g, ifg_b, igh, chF, chI);
  k_scan2<<<dim3(32), dim3(D), 0, stream>>>(chF, chI, init_cx, cst);
  k_scan3<<<dim3(32, NCH), dim3(D), 0, stream>>>(ifg, ifg_ms, ifg_g, ifg_b, igh, cst, cell);

  // 11-12. og GEMM (A = [gh-x | cell] bf16) + final output
  k_mgemm<128, 128, 256, 2, 0, false><<<dim3(512), dim3(512), 0, stream>>>(
      ghb, cell, nullptr, nullptr, nullptr, wt_og, b_og, og,
      nullptr, nullptr, nullptr, nullptr, nullptr, nullptr, nullptr);
  k_og_out<<<dim3(M), dim3(256), 0, stream>>>(og, cell, og_g, og_b, out);
}